// Round 1
// 1349.847 us; speedup vs baseline: 1.3432x; 1.3432x over previous
//
#include <hip/hip_runtime.h>
#include <stdint.h>

#define NN   2048
#define TTT  512
#define NT   (NN * TTT)          /* 1048576 rows */
#define NTM  (NN * (TTT - 1))    /* 1046528 rows */
#define SLOPE 0.01f
#define BN_EPS 1e-5f

typedef unsigned int uint;

/* ---- workspace layout (float offsets inside wts region) ----
   All weights converted to fp32 once by prep_kernel. Main kernels read them
   via uniform addresses from a __restrict__ pointer -> compiler emits s_load
   (SMEM pipe) instead of LDS broadcasts (the old per-CU LDS bottleneck). */
#define W_EW1   0      /* [33][32] row-major, dir row at +1024 */
#define W_EW1C  1056   /* [16][32] combined (W1a+W1b) for inplace branch */
#define W_EB1   1568
#define W_EW2   1600   /* [32][32] */
#define W_EB2   2624
#define W_EW3   2656   /* [32][32] */
#define W_EB3   3680
#define W_NW1   3712   /* [32][32] */
#define W_NB1   4736
#define W_NW2   4768   /* [32][32] */
#define W_NB2   5792
#define W_NW3   5824   /* [32][32] */
#define W_NB3   6848
#define W_TOTAL 6880

__device__ __forceinline__ float bf2f(uint16_t u) {
    union { uint u32; float f; } v; v.u32 = ((uint)u) << 16; return v.f;
}
__device__ __forceinline__ uint16_t f2bf(float f) {
    union { float f; uint u; } v; v.f = f;
    uint r = v.u + 0x7FFFu + ((v.u >> 16) & 1u);   // RTNE
    return (uint16_t)(r >> 16);
}

template <bool F32>
__device__ __forceinline__ float wv(const void* W, int i) {
    return F32 ? ((const float*)W)[i] : bf2f(((const uint16_t*)W)[i]);
}

template <bool F32>
__device__ __forceinline__ void loadrow16(const void* x, size_t elt, float* f) {
    if (F32) {
        const float4* q = (const float4*)((const float*)x + elt);
        float4 a = q[0], b = q[1], c = q[2], d = q[3];
        f[0]=a.x; f[1]=a.y; f[2]=a.z; f[3]=a.w;
        f[4]=b.x; f[5]=b.y; f[6]=b.z; f[7]=b.w;
        f[8]=c.x; f[9]=c.y; f[10]=c.z; f[11]=c.w;
        f[12]=d.x; f[13]=d.y; f[14]=d.z; f[15]=d.w;
    } else {
        const uint4* q = (const uint4*)((const uint16_t*)x + elt);
        uint4 a = q[0], b = q[1];
        uint w[8] = {a.x, a.y, a.z, a.w, b.x, b.y, b.z, b.w};
#pragma unroll
        for (int i = 0; i < 8; i++) {
            union { uint u; float f; } lo, hi;
            lo.u = w[i] << 16; hi.u = w[i] & 0xFFFF0000u;
            f[2*i] = lo.f; f[2*i+1] = hi.f;
        }
    }
}
template <bool F32>
__device__ __forceinline__ void loadrow32(const void* x, size_t elt, float* f) {
    loadrow16<F32>(x, elt, f); loadrow16<F32>(x, elt + 16, f + 16);
}
template <bool F32>
__device__ __forceinline__ void storerow32(void* out, size_t elt, const float* f) {
    if (F32) {
        float4* q = (float4*)((float*)out + elt);
#pragma unroll
        for (int i = 0; i < 8; i++)
            q[i] = make_float4(f[4*i], f[4*i+1], f[4*i+2], f[4*i+3]);
    } else {
        uint w[16];
#pragma unroll
        for (int i = 0; i < 16; i++)
            w[i] = (uint)f2bf(f[2*i]) | ((uint)f2bf(f[2*i+1]) << 16);
        uint4* q = (uint4*)((uint16_t*)out + elt);
        q[0] = make_uint4(w[0], w[1], w[2], w[3]);
        q[1] = make_uint4(w[4], w[5], w[6], w[7]);
        q[2] = make_uint4(w[8], w[9], w[10], w[11]);
        q[3] = make_uint4(w[12], w[13], w[14], w[15]);
    }
}

// h[j] += sum_i W[i*32+j] * in[i].  W is a wave-uniform global fp32 pointer:
// uniform address + __restrict__/noclobber => compiler emits s_load (SMEM),
// weights live in SGPRs, v_fmac reads 1 SGPR + 2 VGPRs. No LDS traffic.
// unroll 2 bounds in-flight SMEM to ~64 SGPRs of weights per chunk.
template <int K>
__device__ __forceinline__ void dense(const float* __restrict__ W, const float* in, float* h) {
#pragma unroll 2
    for (int i = 0; i < K; i++) {
        const float x = in[i];
        const float4* __restrict__ w4 = (const float4*)(W + i * 32);
#pragma unroll
        for (int j = 0; j < 8; j++) {
            float4 w = w4[j];
            h[4*j+0] = fmaf(w.x, x, h[4*j+0]);
            h[4*j+1] = fmaf(w.y, x, h[4*j+1]);
            h[4*j+2] = fmaf(w.z, x, h[4*j+2]);
            h[4*j+3] = fmaf(w.w, x, h[4*j+3]);
        }
    }
}
__device__ __forceinline__ void lrelu32(float* h) {
#pragma unroll
    for (int j = 0; j < 32; j++) h[j] = fmaxf(h[j], h[j] * SLOPE);
}

// full edge 3-layer MLP; dir: 0 (inplace, uses combined W1c), +1 fwd, -1 bwd
template <bool INPLACE>
__device__ __forceinline__ void edge_mlp(
    const float* __restrict__ W1, const float* __restrict__ W1c,
    const float* __restrict__ W2, const float* __restrict__ W3,
    const float* __restrict__ B1, const float* __restrict__ B2, const float* __restrict__ B3,
    const float* xt, const float* xn, float dir, float* o)
{
    float h1[32];
#pragma unroll
    for (int j = 0; j < 32; j++) h1[j] = fmaf(dir, W1[1024 + j], B1[j]);
    if (INPLACE) {
        dense<16>(W1c, xt, h1);
    } else {
        dense<16>(W1, xt, h1);
        dense<16>(W1 + 512, xn, h1);
    }
    lrelu32(h1);
    float h2[32];
#pragma unroll
    for (int j = 0; j < 32; j++) h2[j] = B2[j];
    dense<32>(W2, h1, h2);
    lrelu32(h2);
#pragma unroll
    for (int j = 0; j < 32; j++) o[j] = B3[j];
    dense<32>(W3, h2, o);
}

// wave butterfly reduce of v and v^2 per channel -> LDS atomics (1 lane each)
__device__ __forceinline__ void stats_accum(const float* v, float* dst, int lane) {
#pragma unroll
    for (int j = 0; j < 32; j++) {
        float s = v[j], q = v[j] * v[j];
#pragma unroll
        for (int m = 1; m < 64; m <<= 1) { s += __shfl_xor(s, m, 64); q += __shfl_xor(q, m, 64); }
        if (lane == j) atomicAdd(&dst[j], s);
        if (lane == 32 + j) atomicAdd(&dst[32 + j], q);
    }
}

// ---------------- prep: dtype detect + fp32 weight conversion ----------------
__global__ void prep_kernel(
    const uint* __restrict__ x,
    const void* __restrict__ eW1, const void* __restrict__ eb1,
    const void* __restrict__ eW2, const void* __restrict__ eb2,
    const void* __restrict__ eW3, const void* __restrict__ eb3,
    const void* __restrict__ nW1, const void* __restrict__ nb1,
    const void* __restrict__ nW2, const void* __restrict__ nb2,
    const void* __restrict__ nW3, const void* __restrict__ nb3,
    int* __restrict__ flag, float* __restrict__ wts)
{
    __shared__ int cnt;
    const int tid = threadIdx.x;
    if (tid == 0) cnt = 0;
    __syncthreads();
    if (tid < 64) {
        uint w = x[tid];
        uint e = (w >> 7) & 0xFFu;
        if (e >= 110u && e <= 134u) atomicAdd(&cnt, 1);
    }
    __syncthreads();
    const bool f32 = (cnt < 32);
    if (tid == 0) flag[0] = f32 ? 1 : 0;
    auto rd = [&](const void* p, int i) -> float {
        return f32 ? ((const float*)p)[i] : bf2f(((const uint16_t*)p)[i]);
    };
    for (int i = tid; i < 1056; i += 256) wts[W_EW1 + i] = rd(eW1, i);
    for (int i = tid; i < 512;  i += 256) wts[W_EW1C + i] = rd(eW1, i) + rd(eW1, 512 + i);
    for (int i = tid; i < 1024; i += 256) {
        wts[W_EW2 + i] = rd(eW2, i); wts[W_EW3 + i] = rd(eW3, i);
        wts[W_NW1 + i] = rd(nW1, i); wts[W_NW2 + i] = rd(nW2, i); wts[W_NW3 + i] = rd(nW3, i);
    }
    if (tid < 32) {
        wts[W_EB1 + tid] = rd(eb1, tid); wts[W_EB2 + tid] = rd(eb2, tid); wts[W_EB3 + tid] = rd(eb3, tid);
        wts[W_NB1 + tid] = rd(nb1, tid); wts[W_NB2 + tid] = rd(nb2, tid); wts[W_NB3 + tid] = rd(nb3, tid);
    }
}

// ---------------- pass 1: edge stats (all 3 branches per row) ----------------
template <bool F32>
__global__ __launch_bounds__(256) void edge_stats_kernel(
    const void* __restrict__ x, const float* __restrict__ wts,
    const int* __restrict__ flag, float* __restrict__ gstats /*192*/)
{
    if ((flag[0] != 0) != F32) return;
    __shared__ float sSt[192];
    const int tid = threadIdx.x;
    const int lane = tid & 63;
    if (tid < 192) sSt[tid] = 0.f;
    __syncthreads();

    const float* __restrict__ W1  = wts + W_EW1;
    const float* __restrict__ W1c = wts + W_EW1C;
    const float* __restrict__ W2  = wts + W_EW2;
    const float* __restrict__ W3  = wts + W_EW3;
    const float* __restrict__ B1  = wts + W_EB1;
    const float* __restrict__ B2  = wts + W_EB2;
    const float* __restrict__ B3  = wts + W_EB3;

    const uint r = blockIdx.x * 256u + (uint)tid;   // grid covers NT exactly
    const uint t = r & 511u;
    float xt[16]; loadrow16<F32>(x, (size_t)r << 4, xt);
    float o[32];

    // inplace
    edge_mlp<true>(W1, W1c, W2, W3, B1, B2, B3, xt, xt, 0.f, o);
    stats_accum(o, &sSt[0], lane);

    // fwd: neighbor t-1, valid t>0
    {
        const float vf = (t > 0u) ? 1.f : 0.f;
        const uint rn = (t > 0u) ? r - 1u : r;
        float xn[16]; loadrow16<F32>(x, (size_t)rn << 4, xn);
        edge_mlp<false>(W1, W1c, W2, W3, B1, B2, B3, xt, xn, 1.f, o);
#pragma unroll
        for (int j = 0; j < 32; j++) o[j] *= vf;
        stats_accum(o, &sSt[64], lane);
    }
    // bwd: neighbor t+1, valid t<511
    {
        const float vf = (t < 511u) ? 1.f : 0.f;
        const uint rn = (t < 511u) ? r + 1u : r;
        float xn[16]; loadrow16<F32>(x, (size_t)rn << 4, xn);
        edge_mlp<false>(W1, W1c, W2, W3, B1, B2, B3, xt, xn, -1.f, o);
#pragma unroll
        for (int j = 0; j < 32; j++) o[j] *= vf;
        stats_accum(o, &sSt[128], lane);
    }
    __syncthreads();
    if (tid < 192) atomicAdd(&gstats[tid], sSt[tid]);
}

// ---------------- pass 2: node (recompute branches, aggregate, node MLP) ----------------
template <bool F32>
__global__ __launch_bounds__(256) void node_kernel(
    const void* __restrict__ x, const float* __restrict__ wts,
    const void* __restrict__ egamma, const void* __restrict__ ebeta,
    const int* __restrict__ flag,
    const float* __restrict__ gstats_edge, float* __restrict__ gstats_node,
    void* __restrict__ out)
{
    if ((flag[0] != 0) != F32) return;
    __shared__ float sAff[192];   // per branch: scale[32], shift[32]
    __shared__ float sSt[64];
    const int tid = threadIdx.x;
    const int lane = tid & 63;

    const float* __restrict__ EW1  = wts + W_EW1;
    const float* __restrict__ EW1c = wts + W_EW1C;
    const float* __restrict__ EW2  = wts + W_EW2;
    const float* __restrict__ EW3  = wts + W_EW3;
    const float* __restrict__ EB1  = wts + W_EB1;
    const float* __restrict__ EB2  = wts + W_EB2;
    const float* __restrict__ EB3  = wts + W_EB3;
    const float* __restrict__ NW1  = wts + W_NW1;
    const float* __restrict__ NW2  = wts + W_NW2;
    const float* __restrict__ NW3  = wts + W_NW3;
    const float* __restrict__ NB1  = wts + W_NB1;
    const float* __restrict__ NB2  = wts + W_NB2;
    const float* __restrict__ NB3  = wts + W_NB3;

    if (tid < 32) {
        float g = wv<F32>(egamma, tid), be = wv<F32>(ebeta, tid);
#pragma unroll
        for (int br = 0; br < 3; br++) {
            float cnt = (br == 0) ? (float)NT : (float)NTM;
            float s = gstats_edge[br * 64 + tid], q = gstats_edge[br * 64 + 32 + tid];
            float mu = s / cnt;
            float var = q / cnt - mu * mu;
            float sc = g * rsqrtf(var + BN_EPS);
            sAff[br * 64 + tid] = sc;
            sAff[br * 64 + 32 + tid] = be - mu * sc;
        }
    }
    if (tid < 64) sSt[tid] = 0.f;
    __syncthreads();

    const uint r = blockIdx.x * 256u + (uint)tid;
    const uint t = r & 511u;
    float xt[16]; loadrow16<F32>(x, (size_t)r << 4, xt);
    float agg[32], o[32];

    // inplace
    edge_mlp<true>(EW1, EW1c, EW2, EW3, EB1, EB2, EB3, xt, xt, 0.f, o);
#pragma unroll
    for (int j = 0; j < 32; j++) agg[j] = fmaf(sAff[j], o[j], sAff[32 + j]);

    // fwd
    {
        const float vf = (t > 0u) ? 1.f : 0.f;
        const uint rn = (t > 0u) ? r - 1u : r;
        float xn[16]; loadrow16<F32>(x, (size_t)rn << 4, xn);
        edge_mlp<false>(EW1, EW1c, EW2, EW3, EB1, EB2, EB3, xt, xn, 1.f, o);
#pragma unroll
        for (int j = 0; j < 32; j++) agg[j] += vf * fmaf(sAff[64 + j], o[j], sAff[96 + j]);
    }
    // bwd
    {
        const float vf = (t < 511u) ? 1.f : 0.f;
        const uint rn = (t < 511u) ? r + 1u : r;
        float xn[16]; loadrow16<F32>(x, (size_t)rn << 4, xn);
        edge_mlp<false>(EW1, EW1c, EW2, EW3, EB1, EB2, EB3, xt, xn, -1.f, o);
#pragma unroll
        for (int j = 0; j < 32; j++) agg[j] += vf * fmaf(sAff[128 + j], o[j], sAff[160 + j]);
    }

    // node MLP
    float g1[32];
#pragma unroll
    for (int j = 0; j < 32; j++) g1[j] = NB1[j];
    dense<32>(NW1, agg, g1);
    lrelu32(g1);
    float g2[32];
#pragma unroll
    for (int j = 0; j < 32; j++) g2[j] = NB2[j];
    dense<32>(NW2, g1, g2);
    lrelu32(g2);
    float g3[32];
#pragma unroll
    for (int j = 0; j < 32; j++) g3[j] = NB3[j];
    dense<32>(NW3, g2, g3);

    storerow32<F32>(out, (size_t)r * 32u, g3);
    stats_accum(g3, sSt, lane);
    __syncthreads();
    if (tid < 64) atomicAdd(&gstats_node[tid], sSt[tid]);
}

// ---------------- pass 3: in-place node BN affine ----------------
template <bool F32>
__global__ __launch_bounds__(256) void finalize_kernel(
    const float* __restrict__ gstats_node,
    const void* __restrict__ ngamma, const void* __restrict__ nbeta,
    const int* __restrict__ flag, void* __restrict__ out)
{
    if ((flag[0] != 0) != F32) return;
    __shared__ float sc[32], sh[32];
    const int tid = threadIdx.x;
    if (tid < 32) {
        float s = gstats_node[tid], q = gstats_node[32 + tid];
        float mu = s / (float)NT;
        float var = q / (float)NT - mu * mu;
        float k = wv<F32>(ngamma, tid) * rsqrtf(var + BN_EPS);
        sc[tid] = k; sh[tid] = wv<F32>(nbeta, tid) - mu * k;
    }
    __syncthreads();
    const uint r = blockIdx.x * 256u + (uint)tid;
    float v[32]; loadrow32<F32>(out, (size_t)r * 32u, v);
    float o[32];
#pragma unroll
    for (int j = 0; j < 32; j++) o[j] = fmaf(sc[j], v[j], sh[j]);
    storerow32<F32>(out, (size_t)r * 32u, o);
}

extern "C" void kernel_launch(void* const* d_in, const int* in_sizes, int n_in,
                              void* d_out, int out_size, void* d_ws, size_t ws_size,
                              hipStream_t stream) {
    const void* x   = d_in[0];
    const void* eW1 = d_in[1]; const void* eb1 = d_in[2];
    const void* eW2 = d_in[3]; const void* eb2 = d_in[4];
    const void* eW3 = d_in[5]; const void* eb3 = d_in[6];
    const void* eg  = d_in[7]; const void* ebt = d_in[8];
    const void* nW1 = d_in[9]; const void* nb1 = d_in[10];
    const void* nW2 = d_in[11]; const void* nb2 = d_in[12];
    const void* nW3 = d_in[13]; const void* nb3 = d_in[14];
    const void* ng  = d_in[15]; const void* nbt = d_in[16];

    float* wts   = (float*)d_ws;                       // fp32 weights, ~27 KB
    float* stats = (float*)((char*)d_ws + 32768);      // [0..191] edge, [192..255] node
    int* flag    = (int*)((char*)d_ws + 36864);        // dtype flag: 1 = fp32, 0 = bf16

    hipMemsetAsync((char*)d_ws + 32768, 0, 8192, stream);
    prep_kernel<<<dim3(1), dim3(256), 0, stream>>>((const uint*)x,
        eW1, eb1, eW2, eb2, eW3, eb3, nW1, nb1, nW2, nb2, nW3, nb3, flag, wts);

    dim3 blk(256), grid(NT / 256);
    edge_stats_kernel<true><<<grid, blk, 0, stream>>>(x, wts, flag, stats);
    edge_stats_kernel<false><<<grid, blk, 0, stream>>>(x, wts, flag, stats);
    node_kernel<true><<<grid, blk, 0, stream>>>(x, wts, eg, ebt, flag, stats, stats + 192, d_out);
    node_kernel<false><<<grid, blk, 0, stream>>>(x, wts, eg, ebt, flag, stats, stats + 192, d_out);
    finalize_kernel<true><<<grid, blk, 0, stream>>>(stats + 192, ng, nbt, flag, d_out);
    finalize_kernel<false><<<grid, blk, 0, stream>>>(stats + 192, ng, nbt, flag, d_out);
}